// Round 4
// baseline (149.512 us; speedup 1.0000x reference)
//
#include <hip/hip_runtime.h>
#include <math.h>

// Native 16B vector type (HIP's float4 is a class; the NT builtin needs this).
typedef float fvec4 __attribute__((ext_vector_type(4)));

// ---------------------------------------------------------------------------
// Pass 1: per-batch joint moments of the 2-D points (double precision),
// then closed-form mean/std(ddof=1) of the S*S pairwise dist_sq values.
//   sum_d  = 2N(S2x+S2y) - 2(S1x^2 + S1y^2)
//   sum_d2 = [2N S4x - 8 S3x S1x + 6 S2x^2] + [same for y]
//          + 2*[2N A22 - 4 A21 S1y - 4 A12 S1x + 2 S2x S2y + 4 A11^2]
// One 1024-thread block per batch; wave shuffle reduction, 2 barriers.
// Measured-consistent cost: ~3 us. Error vs true sums ~1e-10 relative.
// ---------------------------------------------------------------------------
__global__ __launch_bounds__(1024) void pab_moments_kernel(
        const float* __restrict__ r, float* __restrict__ thr_out, int S) {
    const int b = blockIdx.x;
    const float2* emb = (const float2*)r + (size_t)b * S;
    const int tid = threadIdx.x;

    double s[12];
#pragma unroll
    for (int k = 0; k < 12; ++k) s[k] = 0.0;

    for (int idx0 = tid * 4; idx0 < S; idx0 += blockDim.x * 4) {
        float4 c0 = *(const float4*)(emb + idx0);
        float4 c1 = *(const float4*)(emb + idx0 + 2);
        float xs[4] = {c0.x, c0.z, c1.x, c1.z};
        float ys[4] = {c0.y, c0.w, c1.y, c1.w};
#pragma unroll
        for (int k = 0; k < 4; ++k) {
            if (idx0 + k >= S) break;
            double x = (double)xs[k], y = (double)ys[k];
            double x2 = x * x, y2 = y * y;
            s[0]  += x;        s[1]  += y;
            s[2]  += x2;       s[3]  += y2;
            s[4]  += x2 * x;   s[5]  += y2 * y;
            s[6]  += x2 * x2;  s[7]  += y2 * y2;
            s[8]  += x * y;    s[9]  += x2 * y;
            s[10] += x * y2;   s[11] += x2 * y2;
        }
    }

#pragma unroll
    for (int off = 32; off > 0; off >>= 1) {
#pragma unroll
        for (int k = 0; k < 12; ++k)
            s[k] += __shfl_down(s[k], off, 64);
    }

    __shared__ double part[16][12];
    __shared__ double tot[12];
    const int wave = tid >> 6, lane = tid & 63;
    const int nwaves = blockDim.x >> 6;
    if (lane == 0) {
#pragma unroll
        for (int k = 0; k < 12; ++k) part[wave][k] = s[k];
    }
    __syncthreads();
    if (tid < 12) {
        double t = 0.0;
        for (int w = 0; w < nwaves; ++w) t += part[w][tid];
        tot[tid] = t;
    }
    __syncthreads();

    if (tid == 0) {
        double N = (double)S;
        double M = N * N;
        double S1x = tot[0], S1y = tot[1], S2x = tot[2], S2y = tot[3];
        double S3x = tot[4], S3y = tot[5], S4x = tot[6], S4y = tot[7];
        double A11 = tot[8], A21 = tot[9], A12 = tot[10], A22 = tot[11];

        double sum_d = 2.0 * N * (S2x + S2y) - 2.0 * (S1x * S1x + S1y * S1y);
        double qx = 2.0 * N * S4x - 8.0 * S3x * S1x + 6.0 * S2x * S2x;
        double qy = 2.0 * N * S4y - 8.0 * S3y * S1y + 6.0 * S2y * S2y;
        double cross = 2.0 * N * A22 - 4.0 * A21 * S1y - 4.0 * A12 * S1x
                     + 2.0 * S2x * S2y + 4.0 * A11 * A11;
        double sum_d2 = qx + qy + 2.0 * cross;

        double mean = sum_d / M;
        double var  = (sum_d2 - sum_d * sum_d / M) / (M - 1.0);  // ddof=1
        thr_out[b] = (float)(mean + 1.25 * sqrt(var));
    }
}

// ---------------------------------------------------------------------------
// Pass 2: write the full [B,S,S] attention map.
// Tile: 16 rows x 1024 cols per 256-thread block, fvec4 NT stores.
// Three uniform paths per tile:
//   (a) fully above diagonal (37.5% of tiles): store zeros only — no loads,
//       no rsqrt, no threshold read.
//   (b) fully below/at diagonal (37.5%): compute without the causal compare.
//   (c) straddling (25%): full per-element causal check.
// forward_bias via 0.5 + 0.5*dx*rsqrt(d2)  (== 0.5*(1+cos(atan2(dy,dx)));
// exactly 1.0 at the zero pair, matching atan2(0,1)=0).
// ---------------------------------------------------------------------------
#define PAB_ROWS 16

__global__ __launch_bounds__(256) void pab_attn_kernel(
        const float* __restrict__ r, const float* __restrict__ thr_ws,
        float* __restrict__ out, int S) {
    const int b = blockIdx.z;
    const int i0 = blockIdx.y * PAB_ROWS;
    const int jt0 = blockIdx.x * (int)blockDim.x * 4;   // tile's first column
    const int j0 = jt0 + (int)threadIdx.x * 4;
    if (j0 >= S) return;

    const int rows = min(PAB_ROWS, S - i0);
    size_t orow = ((size_t)b * S + i0) * S + j0;

    // (a) tile entirely above the diagonal -> all zeros, nothing else to do.
    if (jt0 > i0 + rows - 1) {
        const fvec4 z = {0.0f, 0.0f, 0.0f, 0.0f};
        for (int rr = 0; rr < rows; ++rr) {
            __builtin_nontemporal_store(z, (fvec4*)(out + orow));
            orow += S;
        }
        return;
    }

    const float2* emb = (const float2*)r + (size_t)b * S;
    const float thr = thr_ws[b];

    float4 c0 = *(const float4*)(emb + j0);
    float4 c1 = *(const float4*)(emb + j0 + 2);
    const float xs[4] = {c0.x, c0.z, c1.x, c1.z};
    const float ys[4] = {c0.y, c0.w, c1.y, c1.w};
    const int jtile_last = min(jt0 + (int)blockDim.x * 4, S) - 1;

    if (jtile_last <= i0) {
        // (b) tile entirely at/below the diagonal: no causal compare needed.
        for (int rr = 0; rr < rows; ++rr) {
            const float2 pi = emb[i0 + rr];  // block-uniform -> scalar load
            fvec4 res;
#pragma unroll
            for (int k = 0; k < 4; ++k) {
                float dx = pi.x - xs[k];
                float dy = pi.y - ys[k];
                float d2 = fmaf(dx, dx, dy * dy);
                float bias = (d2 > 0.0f) ? fmaf(0.5f * dx, rsqrtf(d2), 0.5f)
                                         : 1.0f;
                res[k] = (d2 <= thr) ? bias : 0.0f;
            }
            __builtin_nontemporal_store(res, (fvec4*)(out + orow));
            orow += S;
        }
    } else {
        // (c) straddling tile: full check.
        for (int rr = 0; rr < rows; ++rr) {
            const int i = i0 + rr;
            const float2 pi = emb[i];
            fvec4 res;
#pragma unroll
            for (int k = 0; k < 4; ++k) {
                float dx = pi.x - xs[k];
                float dy = pi.y - ys[k];
                float d2 = fmaf(dx, dx, dy * dy);
                float bias = (d2 > 0.0f) ? fmaf(0.5f * dx, rsqrtf(d2), 0.5f)
                                         : 1.0f;
                bool valid = (d2 <= thr) & ((j0 + k) <= i);
                res[k] = valid ? bias : 0.0f;
            }
            __builtin_nontemporal_store(res, (fvec4*)(out + orow));
            orow += S;
        }
    }
}

extern "C" void kernel_launch(void* const* d_in, const int* in_sizes, int n_in,
                              void* d_out, int out_size, void* d_ws, size_t ws_size,
                              hipStream_t stream) {
    const float* r = (const float*)d_in[0];
    float* out = (float*)d_out;
    float* thr = (float*)d_ws;

    // in_sizes[0] = B*S*2, out_size = B*S*S  ->  S = 2*out_size / in_sizes[0]
    long in0 = in_sizes[0];
    int S = (int)((2L * (long)out_size) / in0);
    int B = (int)(in0 / (2L * S));

    pab_moments_kernel<<<dim3(B), dim3(1024), 0, stream>>>(r, thr, S);

    dim3 block(256);
    dim3 grid((S + 1023) / 1024, (S + PAB_ROWS - 1) / PAB_ROWS, B);
    pab_attn_kernel<<<grid, block, 0, stream>>>(r, thr, out, S);
}

// Round 6
// 141.370 us; speedup vs baseline: 1.0576x; 1.0576x over previous
//
#include <hip/hip_runtime.h>
#include <math.h>

// ---------------------------------------------------------------------------
// Single fused kernel. Each block:
//
//   Phase 1 — redundantly recomputes its batch's joint point moments in f64
//   (input is 32 KB/batch, L2-broadcast; ~336 f64 ops/lane, <1 us, paid in
//   parallel by all co-resident blocks). Closed-form mean/std(ddof=1) of the
//   S*S pairwise dist_sq values:
//     sum_d  = 2N(S2x+S2y) - 2(S1x^2 + S1y^2)
//     sum_d2 = [2N S4x - 8 S3x S1x + 6 S2x^2] + [same for y]
//            + 2*[2N A22 - 4 A21 S1y - 4 A12 S1x + 2 S2x S2y + 4 A11^2]
//   Reduction order is identical in every block -> bit-identical threshold.
//   (Fusion removes the old 2-block moments kernel + graph dependency gap.)
//
//   Phase 2 — writes a 16-row x 1024-col tile. Row points are hoisted into
//   16 block-uniform float2s (SGPRs) and the row loop is compile-time
//   unrolled: 16 independent compute+store streams, so the store pipe never
//   stalls on a dependent load chain (the old runtime-trip loop serialized).
//   Tiles fully above the diagonal store zeros only (harness poisons d_out,
//   so zeros MUST be written).
//
//   forward_bias via 0.5 + 0.5*dx*rsqrt(d2) == 0.5*(1+cos(atan2(dy,dx)));
//   exactly 1.0 at the zero pair, matching atan2(0,1)=0.
// ---------------------------------------------------------------------------
#define PAB_ROWS 16
#define PAB_TPB  256   // threads per block; tile width = PAB_TPB*4 columns

__global__ __launch_bounds__(PAB_TPB) void pab_fused_kernel(
        const float* __restrict__ r, float* __restrict__ out, int S) {
    const int b = blockIdx.z;
    const float2* emb = (const float2*)r + (size_t)b * S;
    const int tid = threadIdx.x;

    // ---------------- Phase 1: batch moments (every block) ----------------
    double s[12];
#pragma unroll
    for (int k = 0; k < 12; ++k) s[k] = 0.0;

    for (int idx0 = tid * 4; idx0 < S; idx0 += PAB_TPB * 4) {
        float4 c0 = *(const float4*)(emb + idx0);      // p0, p1
        float4 c1 = *(const float4*)(emb + idx0 + 2);  // p2, p3
        float xs[4] = {c0.x, c0.z, c1.x, c1.z};
        float ys[4] = {c0.y, c0.w, c1.y, c1.w};
#pragma unroll
        for (int k = 0; k < 4; ++k) {
            if (idx0 + k >= S) break;
            double x = (double)xs[k], y = (double)ys[k];
            double x2 = x * x, y2 = y * y;
            s[0]  += x;        s[1]  += y;
            s[2]  += x2;       s[3]  += y2;
            s[4]  += x2 * x;   s[5]  += y2 * y;
            s[6]  += x2 * x2;  s[7]  += y2 * y2;
            s[8]  += x * y;    s[9]  += x2 * y;
            s[10] += x * y2;   s[11] += x2 * y2;
        }
    }

    // Wave (64-lane) shuffle reduction — no barriers.
#pragma unroll
    for (int off = 32; off > 0; off >>= 1) {
#pragma unroll
        for (int k = 0; k < 12; ++k)
            s[k] += __shfl_down(s[k], off, 64);
    }

    __shared__ double part[PAB_TPB / 64][12];
    __shared__ double tot[12];
    __shared__ float thr_sh;
    const int wave = tid >> 6, lane = tid & 63;
    if (lane == 0) {
#pragma unroll
        for (int k = 0; k < 12; ++k) part[wave][k] = s[k];
    }
    __syncthreads();
    if (tid < 12) {
        double t = 0.0;
#pragma unroll
        for (int w = 0; w < PAB_TPB / 64; ++w) t += part[w][tid];
        tot[tid] = t;
    }
    __syncthreads();
    if (tid == 0) {
        double N = (double)S;
        double M = N * N;
        double S1x = tot[0], S1y = tot[1], S2x = tot[2], S2y = tot[3];
        double S3x = tot[4], S3y = tot[5], S4x = tot[6], S4y = tot[7];
        double A11 = tot[8], A21 = tot[9], A12 = tot[10], A22 = tot[11];

        double sum_d = 2.0 * N * (S2x + S2y) - 2.0 * (S1x * S1x + S1y * S1y);
        double qx = 2.0 * N * S4x - 8.0 * S3x * S1x + 6.0 * S2x * S2x;
        double qy = 2.0 * N * S4y - 8.0 * S3y * S1y + 6.0 * S2y * S2y;
        double cross = 2.0 * N * A22 - 4.0 * A21 * S1y - 4.0 * A12 * S1x
                     + 2.0 * S2x * S2y + 4.0 * A11 * A11;
        double sum_d2 = qx + qy + 2.0 * cross;

        double mean = sum_d / M;
        double var  = (sum_d2 - sum_d * sum_d / M) / (M - 1.0);  // ddof=1
        thr_sh = (float)(mean + 1.25 * sqrt(var));
    }
    __syncthreads();
    const float thr = thr_sh;

    // ---------------- Phase 2: write the 16 x 1024 tile ----------------
    const int i0 = blockIdx.y * PAB_ROWS;
    const int jt0 = blockIdx.x * PAB_TPB * 4;   // tile's first column
    const int j0 = jt0 + tid * 4;
    if (j0 >= S) return;

    size_t orow = ((size_t)b * S + i0) * S + j0;

    // Fast path: tile entirely above the diagonal -> zeros only.
    if (jt0 > i0 + PAB_ROWS - 1) {
        const float4 z = {0.0f, 0.0f, 0.0f, 0.0f};
#pragma unroll
        for (int rr = 0; rr < PAB_ROWS; ++rr) {
            if (i0 + rr < S) *(float4*)(out + orow) = z;
            orow += S;
        }
        return;
    }

    // Hoist the 16 block-uniform row points (scalar loads, issued together).
    float2 pis[PAB_ROWS];
#pragma unroll
    for (int rr = 0; rr < PAB_ROWS; ++rr)
        pis[rr] = emb[min(i0 + rr, S - 1)];

    float4 c0 = *(const float4*)(emb + j0);
    float4 c1 = *(const float4*)(emb + j0 + 2);
    const float xs[4] = {c0.x, c0.z, c1.x, c1.z};
    const float ys[4] = {c0.y, c0.w, c1.y, c1.w};

#pragma unroll
    for (int rr = 0; rr < PAB_ROWS; ++rr) {
        const int i = i0 + rr;
        if (i < S) {
            const float2 pi = pis[rr];
            float4 res;
            float* rp = &res.x;
#pragma unroll
            for (int k = 0; k < 4; ++k) {
                float dx = pi.x - xs[k];
                float dy = pi.y - ys[k];
                float d2 = fmaf(dx, dx, dy * dy);
                float bias = (d2 > 0.0f) ? fmaf(0.5f * dx, rsqrtf(d2), 0.5f)
                                         : 1.0f;
                bool valid = (d2 <= thr) & ((j0 + k) <= i);
                rp[k] = valid ? bias : 0.0f;
            }
            *(float4*)(out + orow) = res;
        }
        orow += S;
    }
}

extern "C" void kernel_launch(void* const* d_in, const int* in_sizes, int n_in,
                              void* d_out, int out_size, void* d_ws, size_t ws_size,
                              hipStream_t stream) {
    const float* r = (const float*)d_in[0];
    float* out = (float*)d_out;
    (void)d_ws; (void)ws_size;

    // in_sizes[0] = B*S*2, out_size = B*S*S  ->  S = 2*out_size / in_sizes[0]
    long in0 = in_sizes[0];
    int S = (int)((2L * (long)out_size) / in0);
    int B = (int)(in0 / (2L * S));

    dim3 block(PAB_TPB);
    dim3 grid((S + PAB_TPB * 4 - 1) / (PAB_TPB * 4),
              (S + PAB_ROWS - 1) / PAB_ROWS, B);
    pab_fused_kernel<<<grid, block, 0, stream>>>(r, out, S);
}